// Round 14
// baseline (112.063 us; speedup 1.0000x reference)
//
#include <hip/hip_runtime.h>
#include <hip/hip_fp16.h>
#include <math.h>

typedef unsigned long long u64;

constexpr int B = 512, T = 512, C = 128, L = 64;
constexpr int BLANK = C - 1;      // 127
constexpr float INV_LN2 = 1.44269504088896f;
constexpr float LN2 = 0.69314718055995f;
constexpr int PITCH = 66;         // halves per LDS row in rowstats transpose

// ---------------------------------------------------------------------------
// async global->LDS (Myers staging only)
// ---------------------------------------------------------------------------
typedef const __attribute__((address_space(1))) void* gas_p;
typedef __attribute__((address_space(3))) void* las_p;
__device__ __forceinline__ void gload_lds16(const void* g, void* l) {
  __builtin_amdgcn_global_load_lds((gas_p)g, (las_p)l, 16, 0, 0);
}
#define WAIT_VM0() do { \
  asm volatile("s_waitcnt vmcnt(0)" ::: "memory"); \
  __builtin_amdgcn_sched_barrier(0); } while (0)

// ---------------------------------------------------------------------------
// DPP / lane helpers
// ---------------------------------------------------------------------------
__device__ __forceinline__ float dpp_shr1_f(float x, float old) {
  int r = __builtin_amdgcn_update_dpp(__float_as_int(old), __float_as_int(x),
                                      0x138, 0xf, 0xf, false);  // wave_shr:1
  return __int_as_float(r);
}
__device__ __forceinline__ int dpp_shr1_i(int x, int old) {
  return __builtin_amdgcn_update_dpp(old, x, 0x138, 0xf, 0xf, false);
}
__device__ __forceinline__ float scan_max64(float x) {
  const int NI = (int)0xff800000;  // -inf
  int t;
  t = __builtin_amdgcn_update_dpp(NI, __float_as_int(x), 0x111, 0xf, 0xf, false);
  x = fmaxf(x, __int_as_float(t));
  t = __builtin_amdgcn_update_dpp(NI, __float_as_int(x), 0x112, 0xf, 0xf, false);
  x = fmaxf(x, __int_as_float(t));
  t = __builtin_amdgcn_update_dpp(NI, __float_as_int(x), 0x114, 0xf, 0xf, false);
  x = fmaxf(x, __int_as_float(t));
  t = __builtin_amdgcn_update_dpp(NI, __float_as_int(x), 0x118, 0xf, 0xf, false);
  x = fmaxf(x, __int_as_float(t));
  t = __builtin_amdgcn_update_dpp(NI, __float_as_int(x), 0x142, 0xa, 0xf, false);
  x = fmaxf(x, __int_as_float(t));
  t = __builtin_amdgcn_update_dpp(NI, __float_as_int(x), 0x143, 0xc, 0xf, false);
  x = fmaxf(x, __int_as_float(t));
  return x;  // lane63 = wave max
}
__device__ __forceinline__ float scan_add64(float x) {
  int t;
  t = __builtin_amdgcn_update_dpp(0, __float_as_int(x), 0x111, 0xf, 0xf, false);
  x += __int_as_float(t);
  t = __builtin_amdgcn_update_dpp(0, __float_as_int(x), 0x112, 0xf, 0xf, false);
  x += __int_as_float(t);
  t = __builtin_amdgcn_update_dpp(0, __float_as_int(x), 0x114, 0xf, 0xf, false);
  x += __int_as_float(t);
  t = __builtin_amdgcn_update_dpp(0, __float_as_int(x), 0x118, 0xf, 0xf, false);
  x += __int_as_float(t);
  t = __builtin_amdgcn_update_dpp(0, __float_as_int(x), 0x142, 0xa, 0xf, false);
  x += __int_as_float(t);
  t = __builtin_amdgcn_update_dpp(0, __float_as_int(x), 0x143, 0xc, 0xf, false);
  x += __int_as_float(t);
  return x;  // lane63 = wave sum
}
__device__ __forceinline__ float readlane63(float x) {
  return __int_as_float(__builtin_amdgcn_readlane(__float_as_int(x), 63));
}
__device__ __forceinline__ float readlane_f(float v, int k) {
  return __int_as_float(__builtin_amdgcn_readlane(__float_as_int(v), k));
}

// ---------------------------------------------------------------------------
// K1: per-(b,t) row stats (probabilities). p_lab[b][j][t] f16 transposed;
// p_bl[b][t] f32; predc u8; eqm u64 ballot (Myers Peq row).
// ---------------------------------------------------------------------------
__global__ __launch_bounds__(256) void rowstats_kernel(
    const float* __restrict__ logits, const int* __restrict__ labels,
    __half* __restrict__ p_lab, float* __restrict__ p_bl,
    unsigned char* __restrict__ predc, u64* __restrict__ eqm) {
  __shared__ __half slp[64 * PITCH];
  int b = blockIdx.x & 511;
  int t0 = (blockIdx.x >> 9) << 6;
  int w = threadIdx.x >> 6;
  int lane = threadIdx.x & 63;
  int lab = labels[((size_t)b << 6) + lane];
  for (int i = 0; i < 16; ++i) {
    int t = t0 + w * 16 + i;
    const float* rp = logits + (size_t)(b * T + t) * C;
    float v1 = rp[lane];
    float v2 = rp[lane + 64];
    float m = readlane63(scan_max64(fmaxf(v1, v2)));
    unsigned long long b1 = __ballot(v1 == m);
    unsigned long long b2 = __ballot(v2 == m);
    int idx = b1 ? (__ffsll(b1) - 1) : (64 + __ffsll(b2) - 1);
    u64 eqmask = __ballot(lab == idx);
    float e1 = __builtin_amdgcn_exp2f((v1 - m) * INV_LN2);
    float e2 = __builtin_amdgcn_exp2f((v2 - m) * INV_LN2);
    float rs = __builtin_amdgcn_rcpf(readlane63(scan_add64(e1 + e2)));
    float p1 = e1 * rs;
    float p2 = e2 * rs;
    float g1 = __shfl(p1, lab & 63);
    float g2 = __shfl(p2, lab & 63);
    float gp = (lab < 64) ? g1 : g2;
    slp[lane * PITCH + (t - t0)] = __float2half(gp);
    if (lane == 63) p_bl[b * T + t] = p2;   // class 127 = blank
    if (lane == 0) { predc[b * T + t] = (unsigned char)idx; eqm[b * T + t] = eqmask; }
  }
  __syncthreads();
  int j = threadIdx.x >> 2, q = threadIdx.x & 3;
  unsigned wbuf[8];
#pragma unroll
  for (int wd = 0; wd < 8; ++wd)
    wbuf[wd] = ((const unsigned*)slp)[j * (PITCH / 2) + q * 8 + wd];
  uint4 o0 = make_uint4(wbuf[0], wbuf[1], wbuf[2], wbuf[3]);
  uint4 o1 = make_uint4(wbuf[4], wbuf[5], wbuf[6], wbuf[7]);
  uint4* dst = (uint4*)(p_lab + ((size_t)((b << 6) + j)) * T + t0 + q * 16);
  dst[0] = o0;
  dst[1] = o1;
}

// ---------------------------------------------------------------------------
// CTC step (R13-proven BFP prob-domain) + renorm.
// ---------------------------------------------------------------------------
__device__ __forceinline__ void ctc_step_p(float pl, float pb, bool skip_ok,
                                           float& qE, float& qO, int& m,
                                           float& q0, int& m0) {
  float pE = dpp_shr1_f(qE, q0);
  float pO = dpp_shr1_f(qO, 0.0f);
  int mN = dpp_shr1_i(m, m0);
  int dm = mN - m;
  float pEs = ldexpf(pE, dm);
  float pOs = ldexpf(pO, dm);
  float a3 = skip_ok ? pOs : 0.0f;
  float nO = (qO + pEs + a3) * pl;
  float nE = (qE + qO) * pb;
  q0 *= pb;
  qE = nE; qO = nO;
}
__device__ __forceinline__ void renorm_q(float& qE, float& qO, int& m,
                                         float& q0, int& m0) {
  float mx = fmaxf(qE, qO);
  int mprev = dpp_shr1_i(m, m0);
  int e = (__float_as_int(mx) >> 23) & 0xff;
  bool dead = (mx == 0.0f);
  int sh = e - 127;
  qE = ldexpf(qE, -sh);
  qO = ldexpf(qO, -sh);
  m = dead ? mprev : (m + sh);
  int e0 = ((__float_as_int(q0) >> 23) & 0xff) - 127;
  q0 = ldexpf(q0, -e0);
  m0 += e0;
}

// extract half #k (0..15) from 2 uint4 regs (k compile-time)
__device__ __forceinline__ float geth16(const uint4& v0, const uint4& v1, int k) {
  const uint4& v = (k < 8) ? v0 : v1;
  int c2 = (k >> 1) & 3;
  unsigned comp = (c2 == 0) ? v.x : (c2 == 1) ? v.y : (c2 == 2) ? v.z : v.w;
  unsigned hs = (k & 1) ? (comp >> 16) : (comp & 0xffffu);
  unsigned short us = (unsigned short)hs;
  __half h;
  __builtin_memcpy(&h, &us, 2);
  return __half2float(h);
}

// ---------------------------------------------------------------------------
// K2a: CTC forward. One wave per sample. Uniform 16-step groups; A/B register
// double-buffer loaded 2 groups ahead (body ~5KB -> I$-resident).
// ---------------------------------------------------------------------------
__global__ __launch_bounds__(64, 1) void ctc_kernel(
    const __half* __restrict__ p_lab, const float* __restrict__ p_bl,
    const int* __restrict__ labels, const int* __restrict__ label_len,
    const int* __restrict__ logit_len, float* __restrict__ loss_b) {
  int lane = threadIdx.x;
  int b = blockIdx.x;
  int tl = logit_len[b];
  int ll = label_len[b];
  int lab = labels[((size_t)b << 6) + lane];
  int labp = __shfl_up(lab, 1);
  bool skip_ok = (lane > 0) && (lab != labp);
  const uint4* pl4 = (const uint4*)(p_lab + ((size_t)((b << 6) + lane)) * T);
  const float* pbb = p_bl + (size_t)b * T;
  float qE = 0.0f, qO, q0;
  int m = 0, m0 = 0;

  if (tl == T) {
    uint4 A0 = pl4[0], A1 = pl4[1];
    float sA = pbb[lane];                  // lanes 0..15 used per group
    uint4 B0 = pl4[2], B1 = pl4[3];
    float sB = pbb[16 + lane];

    // group 0 (peeled t=0 init), steps 1..15
    q0 = readlane_f(sA, 0);
    qO = (lane == 0) ? geth16(A0, A1, 0) : 0.0f;
#pragma unroll
    for (int kk = 1; kk < 16; ++kk) {
      ctc_step_p(geth16(A0, A1, kk), readlane_f(sA, kk), skip_ok,
                 qE, qO, m, q0, m0);
      if ((kk & 3) == 3) renorm_q(qE, qO, m, q0, m0);
    }
    A0 = pl4[4]; A1 = pl4[5]; sA = pbb[32 + lane];   // load group 2

#pragma unroll 1
    for (int g = 1; g < 31; g += 2) {
      // consume group g from B, prefetch group g+2 into B
#pragma unroll
      for (int kk = 0; kk < 16; ++kk) {
        ctc_step_p(geth16(B0, B1, kk), readlane_f(sB, kk), skip_ok,
                   qE, qO, m, q0, m0);
        if ((kk & 3) == 3) renorm_q(qE, qO, m, q0, m0);
      }
      B0 = pl4[(g + 2) * 2]; B1 = pl4[(g + 2) * 2 + 1];
      sB = pbb[(g + 2) * 16 + lane];       // overread past row is harmless
      // consume group g+1 from A, prefetch group g+3 into A
#pragma unroll
      for (int kk = 0; kk < 16; ++kk) {
        ctc_step_p(geth16(A0, A1, kk), readlane_f(sA, kk), skip_ok,
                   qE, qO, m, q0, m0);
        if ((kk & 3) == 3) renorm_q(qE, qO, m, q0, m0);
      }
      A0 = pl4[(g + 3) * 2]; A1 = pl4[(g + 3) * 2 + 1];
      sA = pbb[(g + 3) * 16 + lane];
    }
    // group 31 from B
#pragma unroll
    for (int kk = 0; kk < 16; ++kk) {
      ctc_step_p(geth16(B0, B1, kk), readlane_f(sB, kk), skip_ok,
                 qE, qO, m, q0, m0);
      if ((kk & 3) == 3) renorm_q(qE, qO, m, q0, m0);
    }
  } else {
    // general fallback (not exercised by this input shape)
    const __half* plh = (const __half*)pl4;
    q0 = pbb[0];
    qO = (lane == 0) ? __half2float(plh[0]) : 0.0f;
    for (int t = 1; t < tl; ++t) {
      ctc_step_p(__half2float(plh[t]), pbb[t], skip_ok, qE, qO, m, q0, m0);
      if ((t & 3) == 3) renorm_q(qE, qO, m, q0, m0);
    }
  }
  float e1 = __shfl(qE, ll - 1);
  float e2 = __shfl(qO, ll - 1);
  int msel = __shfl(m, ll - 1);
  if (lane == 0) {
    float r = (float)msel + __builtin_amdgcn_logf(e1 + e2);   // log2 total
    loss_b[b] = -r * LN2;
  }
}

// ---------------------------------------------------------------------------
// K2b: Myers bit-parallel edit distance (lane = sample), LDS-staged (R12).
// ---------------------------------------------------------------------------
__device__ __forceinline__ void ed_step(u64 eq, int cc, int shift, bool tok,
                                        u64& Pv, u64& Mv, int& score, int& prevc) {
  bool keep = (cc != BLANK) && (cc != prevc) && tok;
  u64 Xv = eq | Mv;
  u64 Xh = (((eq & Pv) + Pv) ^ Pv) | eq;
  u64 Ph = Mv | ~(Xh | Pv);
  u64 Mh = Pv & Xh;
  int d = (int)((Ph >> shift) & 1ULL) - (int)((Mh >> shift) & 1ULL);
  score += keep ? d : 0;
  Ph = (Ph << 1) | 1ULL;
  Mh <<= 1;
  u64 nPv = Mh | ~(Xv | Ph);
  u64 nMv = Ph & Xv;
  Pv = keep ? nPv : Pv;
  Mv = keep ? nMv : Mv;
  prevc = cc;
}

__global__ __launch_bounds__(64, 1) void myers_kernel(
    const unsigned char* __restrict__ predc, const u64* __restrict__ eqm,
    const int* __restrict__ label_len, const int* __restrict__ logit_len,
    float* __restrict__ ler_b) {
  __shared__ char smem[36864];
  int lane = threadIdx.x;
  int bb = (blockIdx.x << 6) + lane;
  int tl = logit_len[bb];
  int ll = label_len[bb];
  int shift = ll - 1;
  u64 Pv = ~0ULL, Mv = 0ULL;
  int score = ll;
  int prevc = 255;
  const char* eqB = (const char*)(eqm + (size_t)bb * T);
  const char* pqB = (const char*)(predc + (size_t)bb * T);
  auto stage = [&](int c, int s) {
    char* Eb = smem + s * 18432;
#pragma unroll
    for (int k = 0; k < 16; ++k)
      gload_lds16(eqB + (size_t)c * 256 + k * 16, Eb + k * 1024);
#pragma unroll
    for (int k = 0; k < 2; ++k)
      gload_lds16(pqB + (size_t)c * 32 + k * 16, Eb + 16384 + k * 1024);
  };
  stage(0, 0);
  WAIT_VM0();
  stage(1, 1);
#pragma unroll 1
  for (int c = 0; c < 16; ++c) {
    int s = c & 1;
    if (c) {
      WAIT_VM0();
      if (c < 15) stage(c + 1, s ^ 1);
    }
    const u64* ep = (const u64*)(smem + s * 18432);
    const unsigned char* pp = (const unsigned char*)(smem + s * 18432 + 16384);
#pragma unroll
    for (int k = 0; k < 32; ++k) {
      u64 eq = ep[(k >> 1) * 128 + lane * 2 + (k & 1)];
      int cc = pp[(k >> 4) * 1024 + lane * 16 + (k & 15)];
      ed_step(eq, cc, shift, c * 32 + k < tl, Pv, Mv, score, prevc);
    }
  }
  ler_b[bb] = (float)score / (float)ll;
}

// ---------------------------------------------------------------------------
// K3: deterministic final mean over B for loss and ler.
// ---------------------------------------------------------------------------
__global__ __launch_bounds__(512) void reduce_kernel(
    const float* __restrict__ loss_b, const float* __restrict__ ler_b,
    float* __restrict__ out) {
  __shared__ float sl[512];
  __shared__ float sr[512];
  int tid = threadIdx.x;
  sl[tid] = loss_b[tid];
  sr[tid] = ler_b[tid];
  __syncthreads();
  for (int off = 256; off; off >>= 1) {
    if (tid < off) { sl[tid] += sl[tid + off]; sr[tid] += sr[tid + off]; }
    __syncthreads();
  }
  if (tid == 0) {
    out[0] = sl[0] / (float)B;
    out[1] = sr[0] / (float)B;
  }
}

extern "C" void kernel_launch(void* const* d_in, const int* in_sizes, int n_in,
                              void* d_out, int out_size, void* d_ws, size_t ws_size,
                              hipStream_t stream) {
  const int*   labels    = (const int*)d_in[0];
  const float* logits    = (const float*)d_in[1];
  const int*   label_len = (const int*)d_in[2];
  const int*   logit_len = (const int*)d_in[3];
  float* out = (float*)d_out;

  char* ws = (char*)d_ws;
  const size_t OFF_BL   = (size_t)B * T * 64 * 2;        // after 32MB p_lab
  const size_t OFF_EQM  = OFF_BL + (size_t)B * T * 4;    // after 1MB p_bl
  const size_t OFF_PRED = OFF_EQM + (size_t)B * T * 8;   // after 2MB eqm
  const size_t OFF_RED  = OFF_PRED + (size_t)B * T;      // after 0.25MB predc
  __half* p_lab = (__half*)ws;
  float*  p_bl  = (float*)(ws + OFF_BL);
  u64*    eqm   = (u64*)(ws + OFF_EQM);
  unsigned char* predc = (unsigned char*)(ws + OFF_PRED);
  float*  loss_b = (float*)(ws + OFF_RED);
  float*  ler_b  = loss_b + B;

  rowstats_kernel<<<B * (T / 64), 256, 0, stream>>>(logits, labels, p_lab,
                                                    p_bl, predc, eqm);
  myers_kernel<<<8, 64, 0, stream>>>(predc, eqm, label_len, logit_len, ler_b);
  ctc_kernel<<<B, 64, 0, stream>>>(p_lab, p_bl, labels, label_len, logit_len,
                                   loss_b);
  reduce_kernel<<<1, 512, 0, stream>>>(loss_b, ler_b, out);
}

// Round 15
// 94.667 us; speedup vs baseline: 1.1838x; 1.1838x over previous
//
#include <hip/hip_runtime.h>
#include <hip/hip_fp16.h>
#include <math.h>

typedef unsigned long long u64;

constexpr int B = 512, T = 512, C = 128, L = 64;
constexpr int BLANK = C - 1;      // 127
constexpr float INV_LN2 = 1.44269504088896f;
constexpr float LN2 = 0.69314718055995f;
constexpr int PITCH = 66;         // halves per LDS row in rowstats transpose
constexpr int RSTRIDE = 520;      // halves per p_lab row (T + 8 pad, 16B-mult)

// ---------------------------------------------------------------------------
// async global->LDS (Myers staging only)
// ---------------------------------------------------------------------------
typedef const __attribute__((address_space(1))) void* gas_p;
typedef __attribute__((address_space(3))) void* las_p;
__device__ __forceinline__ void gload_lds16(const void* g, void* l) {
  __builtin_amdgcn_global_load_lds((gas_p)g, (las_p)l, 16, 0, 0);
}
#define WAIT_VM0() do { \
  asm volatile("s_waitcnt vmcnt(0)" ::: "memory"); \
  __builtin_amdgcn_sched_barrier(0); } while (0)

// ---------------------------------------------------------------------------
// DPP / lane helpers
// ---------------------------------------------------------------------------
__device__ __forceinline__ float dpp_shr1_f(float x, float old) {
  int r = __builtin_amdgcn_update_dpp(__float_as_int(old), __float_as_int(x),
                                      0x138, 0xf, 0xf, false);  // wave_shr:1
  return __int_as_float(r);
}
__device__ __forceinline__ int dpp_shr1_i(int x, int old) {
  return __builtin_amdgcn_update_dpp(old, x, 0x138, 0xf, 0xf, false);
}
__device__ __forceinline__ float scan_max64(float x) {
  const int NI = (int)0xff800000;  // -inf
  int t;
  t = __builtin_amdgcn_update_dpp(NI, __float_as_int(x), 0x111, 0xf, 0xf, false);
  x = fmaxf(x, __int_as_float(t));
  t = __builtin_amdgcn_update_dpp(NI, __float_as_int(x), 0x112, 0xf, 0xf, false);
  x = fmaxf(x, __int_as_float(t));
  t = __builtin_amdgcn_update_dpp(NI, __float_as_int(x), 0x114, 0xf, 0xf, false);
  x = fmaxf(x, __int_as_float(t));
  t = __builtin_amdgcn_update_dpp(NI, __float_as_int(x), 0x118, 0xf, 0xf, false);
  x = fmaxf(x, __int_as_float(t));
  t = __builtin_amdgcn_update_dpp(NI, __float_as_int(x), 0x142, 0xa, 0xf, false);
  x = fmaxf(x, __int_as_float(t));
  t = __builtin_amdgcn_update_dpp(NI, __float_as_int(x), 0x143, 0xc, 0xf, false);
  x = fmaxf(x, __int_as_float(t));
  return x;  // lane63 = wave max
}
__device__ __forceinline__ float scan_add64(float x) {
  int t;
  t = __builtin_amdgcn_update_dpp(0, __float_as_int(x), 0x111, 0xf, 0xf, false);
  x += __int_as_float(t);
  t = __builtin_amdgcn_update_dpp(0, __float_as_int(x), 0x112, 0xf, 0xf, false);
  x += __int_as_float(t);
  t = __builtin_amdgcn_update_dpp(0, __float_as_int(x), 0x114, 0xf, 0xf, false);
  x += __int_as_float(t);
  t = __builtin_amdgcn_update_dpp(0, __float_as_int(x), 0x118, 0xf, 0xf, false);
  x += __int_as_float(t);
  t = __builtin_amdgcn_update_dpp(0, __float_as_int(x), 0x142, 0xa, 0xf, false);
  x += __int_as_float(t);
  t = __builtin_amdgcn_update_dpp(0, __float_as_int(x), 0x143, 0xc, 0xf, false);
  x += __int_as_float(t);
  return x;  // lane63 = wave sum
}
__device__ __forceinline__ float readlane63(float x) {
  return __int_as_float(__builtin_amdgcn_readlane(__float_as_int(x), 63));
}

// ---------------------------------------------------------------------------
// K1: per-(b,t) row stats. Writes:
//   rtab[b][j][col] f16 = pl/pb ratio at col = t + ((2j)&7)  (skew-folded,
//     row stride 520; lane-j group loads are 16B-aligned in the dp kernel)
//   p_blh[b][t] f16 (blank prob, fallback only), predc u8, eqm u64 ballot,
//   pbsum_part[b*8+chunk] f32 = sum over the chunk's 64 t of log2(pb).
// Grid: blockIdx = chunk*512 + b  (all chunks of sample b on XCD b%8).
// ---------------------------------------------------------------------------
__global__ __launch_bounds__(256) void rowstats_kernel(
    const float* __restrict__ logits, const int* __restrict__ labels,
    __half* __restrict__ rtab, __half* __restrict__ p_blh,
    unsigned char* __restrict__ predc, u64* __restrict__ eqm,
    float* __restrict__ pbsum_part) {
  __shared__ __half slp[64 * PITCH];
  __shared__ float sp[4];
  int b = blockIdx.x & 511;
  int chunk = blockIdx.x >> 9;
  int t0 = chunk << 6;
  int w = threadIdx.x >> 6;
  int lane = threadIdx.x & 63;
  int lab = labels[((size_t)b << 6) + lane];
  float acc = 0.0f;
  for (int i = 0; i < 16; ++i) {
    int t = t0 + w * 16 + i;
    const float* rp = logits + (size_t)(b * T + t) * C;
    float v1 = rp[lane];
    float v2 = rp[lane + 64];
    float m = readlane63(scan_max64(fmaxf(v1, v2)));
    unsigned long long b1 = __ballot(v1 == m);
    unsigned long long b2 = __ballot(v2 == m);
    int idx = b1 ? (__ffsll(b1) - 1) : (64 + __ffsll(b2) - 1);
    u64 eqmask = __ballot(lab == idx);
    float e1 = __builtin_amdgcn_exp2f((v1 - m) * INV_LN2);
    float e2 = __builtin_amdgcn_exp2f((v2 - m) * INV_LN2);
    float rs = __builtin_amdgcn_rcpf(readlane63(scan_add64(e1 + e2)));
    float p1 = e1 * rs;
    float p2 = e2 * rs;        // lane63: blank prob
    acc += __builtin_amdgcn_logf(p2);   // log2; only lane63's acc used
    float pbv = readlane63(p2);         // blank prob broadcast
    float g1 = __shfl(p1, lab & 63);
    float g2 = __shfl(p2, lab & 63);
    float gp = (lab < 64) ? g1 : g2;
    float ratio = gp * __builtin_amdgcn_rcpf(pbv);
    slp[lane * PITCH + (t - t0)] = __float2half(ratio);
    if (lane == 63) p_blh[b * T + t] = __float2half(p2);
    if (lane == 0) { predc[b * T + t] = (unsigned char)idx; eqm[b * T + t] = eqmask; }
  }
  if (lane == 63) sp[w] = acc;
  __syncthreads();
  if (threadIdx.x == 0)
    pbsum_part[(b << 3) + chunk] = sp[0] + sp[1] + sp[2] + sp[3];
  // transpose writeout: thread (j = tid/4, q = tid%4) -> 16 halves of row j at
  // col t0 + q*16 + sj (sj = (2j)&7, even -> 4B-aligned dword stores)
  int j = threadIdx.x >> 2, q = threadIdx.x & 3;
  int sj = (2 * j) & 7;
  unsigned* dstw =
      (unsigned*)(rtab + ((size_t)((b << 6) + j)) * RSTRIDE + t0 + q * 16 + sj);
#pragma unroll
  for (int wd = 0; wd < 8; ++wd)
    dstw[wd] = ((const unsigned*)slp)[j * (PITCH / 2) + q * 8 + wd];
}

// extract half #u (0..7) from a uint4 (u compile-time after unroll)
__device__ __forceinline__ float geth8(const uint4& v, int u) {
  unsigned comp = (u < 2) ? v.x : (u < 4) ? v.y : (u < 6) ? v.z : v.w;
  unsigned hs = (u & 1) ? (comp >> 16) : (comp & 0xffffu);
  unsigned short us = (unsigned short)hs;
  __half h;
  __builtin_memcpy(&h, &us, 2);
  return __half2float(h);
}

// Myers/Hyyrö bit-parallel Levenshtein step (lane = one sample; select-only).
__device__ __forceinline__ void ed_step(u64 eq, int cc, int shift, bool tok,
                                        u64& Pv, u64& Mv, int& score, int& prevc) {
  bool keep = (cc != BLANK) && (cc != prevc) && tok;
  u64 Xv = eq | Mv;
  u64 Xh = (((eq & Pv) + Pv) ^ Pv) | eq;
  u64 Ph = Mv | ~(Xh | Pv);
  u64 Mh = Pv & Xh;
  int d = (int)((Ph >> shift) & 1ULL) - (int)((Mh >> shift) & 1ULL);
  score += keep ? d : 0;
  Ph = (Ph << 1) | 1ULL;
  Mh <<= 1;
  u64 nPv = Mh | ~(Xv | Ph);
  u64 nMv = Ph & Xv;
  Pv = keep ? nPv : Pv;
  Mv = keep ? nMv : Mv;
  prevc = cc;
}

// ---------------------------------------------------------------------------
// K2 fused. Blocks [0,8): Myers edit distance. Blocks [8,8+B): time-skewed
// CTC: lane j computes t = i - 2j; neighbor (post t-1) comes from a 4-deep
// register history via DPP (written 3 iters earlier -> off the chain).
// beta-normalized recursion: nO = (qO + pE' + skip*pO')*r, nE = qE + qO.
// Per-lane BFP scale m; renorm every 4 iters. Operand stream r is one
// aligned uint4 (8 steps) per lane per group, double-buffered.
// ---------------------------------------------------------------------------
__global__ __launch_bounds__(64, 1) void dp_kernel(
    const __half* __restrict__ rtab, const __half* __restrict__ p_blh,
    const unsigned char* __restrict__ predc, const u64* __restrict__ eqm,
    const int* __restrict__ labels, const int* __restrict__ label_len,
    const int* __restrict__ logit_len, const float* __restrict__ pbsum_part,
    float* __restrict__ loss_b, float* __restrict__ ler_b) {
  __shared__ char smem[36864];   // Myers blocks only
  int lane = threadIdx.x;

  if (blockIdx.x >= 8) {
    // ---------------- skewed CTC ----------------
    int b = blockIdx.x - 8;
    int tl = logit_len[b];
    int ll = label_len[b];
    int lab = labels[((size_t)b << 6) + lane];
    int labp = __shfl_up(lab, 1);
    bool skip_ok = (lane > 0) && (lab != labp);
    const char* rowp =
        (const char*)(rtab + ((size_t)((b << 6) + lane)) * RSTRIDE);
    int laneq = lane >> 2;

    float qE = 0.0f, qO = 0.0f;
    int m = 0;
    float hE[4] = {0, 0, 0, 0}, hO[4] = {0, 0, 0, 0};
    int hM[4] = {0, 0, 0, 0};

#define LOAD_GRP(G) \
    (*(const uint4*)(rowp + (size_t)(min(max(8 * ((G) - laneq), 0), 512) * 2)))

#define CONSUME_GRP(BUF, G, MASKED)                                          \
    {                                                                        \
      int tb = 8 * (G) - 2 * lane;                                           \
      (void)tb;                                                              \
      _Pragma("unroll")                                                      \
      for (int u = 0; u < 8; ++u) {                                          \
        float rv = geth8(BUF, u);                                            \
        int ns = (u + 1) & 3;                                                \
        float pE = dpp_shr1_f(hE[ns], 1.0f);                                 \
        float pO = dpp_shr1_f(hO[ns], 0.0f);                                 \
        int mN = dpp_shr1_i(hM[ns], 0);                                      \
        int dm = mN - m;                                                     \
        float pEs = ldexpf(pE, dm);                                          \
        float a3 = skip_ok ? ldexpf(pO, dm) : 0.0f;                          \
        float nO = (qO + pEs + a3) * rv;                                     \
        float nE = qE + qO;                                                  \
        if (MASKED) {                                                        \
          bool act = (unsigned)(tb + u) < (unsigned)tl;                      \
          nO = act ? nO : qO;                                                \
          nE = act ? nE : qE;                                                \
        }                                                                    \
        qO = nO; qE = nE;                                                    \
        if ((u & 3) == 3) {                                                  \
          float mx = fmaxf(qE, qO);                                          \
          int mprev = dpp_shr1_i(m, 0);                                      \
          int e = (__float_as_int(mx) >> 23) & 0xff;                         \
          int sh = e - 127;                                                  \
          qE = ldexpf(qE, -sh);                                              \
          qO = ldexpf(qO, -sh);                                              \
          m = (mx == 0.0f) ? mprev : (m + sh);                               \
        }                                                                    \
        hE[u & 3] = qE; hO[u & 3] = qO; hM[u & 3] = m;                       \
      }                                                                      \
    }

    uint4 bufA = LOAD_GRP(0);
    uint4 bufB = LOAD_GRP(1);
    if (tl == T) {
      // prologue: groups 0..15 (iters 0..127), masked
#pragma unroll 1
      for (int g = 0; g < 16; g += 2) {
        CONSUME_GRP(bufA, g, true);
        bufA = LOAD_GRP(g + 2);
        CONSUME_GRP(bufB, g + 1, true);
        bufB = LOAD_GRP(g + 3);
      }
      // steady: groups 16..63 (iters 128..511), all lanes active
#pragma unroll 1
      for (int g = 16; g < 64; g += 2) {
        CONSUME_GRP(bufA, g, false);
        bufA = LOAD_GRP(g + 2);
        CONSUME_GRP(bufB, g + 1, false);
        bufB = LOAD_GRP(g + 3);
      }
      // epilogue: groups 64..79 (iters 512..639), masked
#pragma unroll 1
      for (int g = 64; g < 80; g += 2) {
        CONSUME_GRP(bufA, g, true);
        bufA = LOAD_GRP(g + 2);
        CONSUME_GRP(bufB, g + 1, true);
        bufB = LOAD_GRP(g + 3);
      }
    } else {
      int ngroups = (tl + 126 + 7) >> 3;
#pragma unroll 1
      for (int g = 0; g < ngroups; g += 2) {
        CONSUME_GRP(bufA, g, true);
        bufA = LOAD_GRP(g + 2);
        CONSUME_GRP(bufB, g + 1, true);
        bufB = LOAD_GRP(g + 3);
      }
    }
#undef LOAD_GRP
#undef CONSUME_GRP

    // lane ll-1 holds beta[2ll-1]=qO, beta[2ll]=qE scaled by 2^m.
    float e1 = __shfl(qE, ll - 1);
    float e2 = __shfl(qO, ll - 1);
    int msel = __shfl(m, ll - 1);
    if (lane == 0) {
      float spb = 0.0f;
      if (tl == T) {
#pragma unroll
        for (int c = 0; c < 8; ++c) spb += pbsum_part[(b << 3) + c];
      } else {
        for (int t = 0; t < tl; ++t)
          spb += __builtin_amdgcn_logf(__half2float(p_blh[b * T + t]));
      }
      float r = (float)msel + __builtin_amdgcn_logf(e1 + e2) + spb;  // log2
      loss_b[b] = -r * LN2;
    }
  } else {
    // ---------------- Myers edit distance (lane = sample) ----------------
    int bb = (blockIdx.x << 6) + lane;
    int tl = logit_len[bb];
    int ll = label_len[bb];
    int shift = ll - 1;
    u64 Pv = ~0ULL, Mv = 0ULL;
    int score = ll;
    int prevc = 255;
    const char* eqB = (const char*)(eqm + (size_t)bb * T);
    const char* pqB = (const char*)(predc + (size_t)bb * T);
    auto stage = [&](int c, int s) {
      char* Eb = smem + s * 18432;
#pragma unroll
      for (int k = 0; k < 16; ++k)
        gload_lds16(eqB + (size_t)c * 256 + k * 16, Eb + k * 1024);
#pragma unroll
      for (int k = 0; k < 2; ++k)
        gload_lds16(pqB + (size_t)c * 32 + k * 16, Eb + 16384 + k * 1024);
    };
    stage(0, 0);
    WAIT_VM0();
    stage(1, 1);
#pragma unroll 1
    for (int c = 0; c < 16; ++c) {
      int s = c & 1;
      if (c) {
        WAIT_VM0();
        if (c < 15) stage(c + 1, s ^ 1);
      }
      const u64* ep = (const u64*)(smem + s * 18432);
      const unsigned char* pp = (const unsigned char*)(smem + s * 18432 + 16384);
#pragma unroll
      for (int k = 0; k < 32; ++k) {
        u64 eq = ep[(k >> 1) * 128 + lane * 2 + (k & 1)];
        int cc = pp[(k >> 4) * 1024 + lane * 16 + (k & 15)];
        ed_step(eq, cc, shift, c * 32 + k < tl, Pv, Mv, score, prevc);
      }
    }
    ler_b[bb] = (float)score / (float)ll;
  }
}

// ---------------------------------------------------------------------------
// K3: deterministic final mean over B for loss and ler.
// ---------------------------------------------------------------------------
__global__ __launch_bounds__(512) void reduce_kernel(
    const float* __restrict__ loss_b, const float* __restrict__ ler_b,
    float* __restrict__ out) {
  __shared__ float sl[512];
  __shared__ float sr[512];
  int tid = threadIdx.x;
  sl[tid] = loss_b[tid];
  sr[tid] = ler_b[tid];
  __syncthreads();
  for (int off = 256; off; off >>= 1) {
    if (tid < off) { sl[tid] += sl[tid + off]; sr[tid] += sr[tid + off]; }
    __syncthreads();
  }
  if (tid == 0) {
    out[0] = sl[0] / (float)B;
    out[1] = sr[0] / (float)B;
  }
}

extern "C" void kernel_launch(void* const* d_in, const int* in_sizes, int n_in,
                              void* d_out, int out_size, void* d_ws, size_t ws_size,
                              hipStream_t stream) {
  const int*   labels    = (const int*)d_in[0];
  const float* logits    = (const float*)d_in[1];
  const int*   label_len = (const int*)d_in[2];
  const int*   logit_len = (const int*)d_in[3];
  float* out = (float*)d_out;

  char* ws = (char*)d_ws;
  const size_t SZ_RTAB = (size_t)B * 64 * RSTRIDE * 2;   // ~34.1 MB
  const size_t OFF_BLH  = SZ_RTAB;
  const size_t OFF_EQM  = OFF_BLH + (size_t)B * T * 2;
  const size_t OFF_PRED = OFF_EQM + (size_t)B * T * 8;
  const size_t OFF_PBS  = OFF_PRED + (size_t)B * T;
  const size_t OFF_RED  = OFF_PBS + (size_t)B * 8 * 4;
  __half* rtab  = (__half*)ws;
  __half* p_blh = (__half*)(ws + OFF_BLH);
  u64*    eqm   = (u64*)(ws + OFF_EQM);
  unsigned char* predc = (unsigned char*)(ws + OFF_PRED);
  float*  pbsum_part = (float*)(ws + OFF_PBS);
  float*  loss_b = (float*)(ws + OFF_RED);
  float*  ler_b  = loss_b + B;

  rowstats_kernel<<<B * (T / 64), 256, 0, stream>>>(logits, labels, rtab,
                                                    p_blh, predc, eqm,
                                                    pbsum_part);
  dp_kernel<<<B + 8, 64, 0, stream>>>(rtab, p_blh, predc, eqm, labels,
                                      label_len, logit_len, pbsum_part,
                                      loss_b, ler_b);
  reduce_kernel<<<1, 512, 0, stream>>>(loss_b, ler_b, out);
}